// Round 1
// baseline (3407.173 us; speedup 1.0000x reference)
//
#include <hip/hip_runtime.h>

#define T_TOK 8192
#define D_DIM 2048
#define E_EXP 8
#define I_DIM 4096

typedef __attribute__((ext_vector_type(8))) short short8;            // 8 bf16 (4 VGPRs)
typedef __attribute__((ext_vector_type(8))) unsigned short ushort8;
typedef __attribute__((ext_vector_type(4))) float floatx4;

#define LDS_ST 56  // LDS row stride in ushorts: BK(32)+24 pad -> 112B (16B aligned, even bank spread)

__device__ __forceinline__ unsigned short f2bf(float f) {
    union { float f; unsigned int u; } v;
    v.f = f;
    return (unsigned short)((v.u + 0x7fffu + ((v.u >> 16) & 1u)) >> 16);  // RNE
}

__device__ __forceinline__ ushort8 cvt8(float4 a, float4 b) {
    ushort8 r;
    r[0] = f2bf(a.x); r[1] = f2bf(a.y); r[2] = f2bf(a.z); r[3] = f2bf(a.w);
    r[4] = f2bf(b.x); r[5] = f2bf(b.y); r[6] = f2bf(b.z); r[7] = f2bf(b.w);
    return r;
}

// ---------------- router: logits -> softmax -> top2 (fp32 exact) ----------------
__global__ __launch_bounds__(256) void router_kernel(
    const float* __restrict__ h, const float* __restrict__ rw,
    int* __restrict__ topk_id, float* __restrict__ topk_w)
{
    const int t = blockIdx.x * 4 + (threadIdx.x >> 6);  // one wave per token
    const int lane = threadIdx.x & 63;
    const float* hp = h + (size_t)t * D_DIM;
    float acc[E_EXP];
#pragma unroll
    for (int e = 0; e < E_EXP; ++e) acc[e] = 0.f;
    for (int d = lane; d < D_DIM; d += 64) {
        float hv = hp[d];
#pragma unroll
        for (int e = 0; e < E_EXP; ++e) acc[e] += hv * rw[e * D_DIM + d];
    }
#pragma unroll
    for (int e = 0; e < E_EXP; ++e)
        for (int o = 32; o > 0; o >>= 1) acc[e] += __shfl_xor(acc[e], o, 64);
    if (lane == 0) {
        float mx = acc[0];
#pragma unroll
        for (int e = 1; e < E_EXP; ++e) mx = fmaxf(mx, acc[e]);
        float p[E_EXP]; float s = 0.f;
#pragma unroll
        for (int e = 0; e < E_EXP; ++e) { p[e] = __expf(acc[e] - mx); s += p[e]; }
        int i1 = 0;
#pragma unroll
        for (int e = 1; e < E_EXP; ++e) if (p[e] > p[i1]) i1 = e;
        int i2 = (i1 == 0) ? 1 : 0;
#pragma unroll
        for (int e = 0; e < E_EXP; ++e) if (e != i1 && p[e] > p[i2]) i2 = e;
        float inv = 1.f / s;
        topk_id[t * 2]     = i1; topk_w[t * 2]     = p[i1] * inv;
        topk_id[t * 2 + 1] = i2; topk_w[t * 2 + 1] = p[i2] * inv;
    }
}

// ---------------- routing bookkeeping ----------------
__global__ void count_kernel(const int* __restrict__ topk_id, int* __restrict__ cnt)
{
    const int i = blockIdx.x * 256 + threadIdx.x;  // over 2T entries
    atomicAdd(&cnt[topk_id[i]], 1);
}

__global__ void prefix_kernel(const int* __restrict__ cnt, int* __restrict__ off)
{
    int s = 0;
    for (int e = 0; e < E_EXP; ++e) { off[e] = s; s += cnt[e]; }
}

__global__ void scatter_kernel(const int* __restrict__ topk_id, const float* __restrict__ topk_w,
                               const int* __restrict__ off, int* __restrict__ cnt2,
                               int* __restrict__ tok_row, float* __restrict__ wt_row)
{
    const int i = blockIdx.x * 256 + threadIdx.x;  // over 2T entries
    const int e = topk_id[i];
    const int slot = atomicAdd(&cnt2[e], 1);
    const int rr = off[e] + slot;
    tok_row[rr] = i >> 1;
    wt_row[rr] = topk_w[i];
}

// ---------------- GEMM1: gu = h @ ws[e].T (paired gate/up tiles), fused SiLU ----------------
__global__ __launch_bounds__(256) void gateup_kernel(
    const float* __restrict__ h, const float* __restrict__ ws,
    const int* __restrict__ tok_row, const int* __restrict__ cnt,
    const int* __restrict__ off, unsigned short* __restrict__ act)
{
    const int e  = blockIdx.y >> 6;
    const int mt = blockIdx.y & 63;
    const int ce = cnt[e];
    if (mt * 128 >= ce) return;
    const int nt = blockIdx.x;     // act col tile: gate col nt*128, up col nt*128 + I
    const int base = off[e];

    __shared__ unsigned short As[128 * LDS_ST];
    __shared__ unsigned short Bg[128 * LDS_ST];
    __shared__ unsigned short Bu[128 * LDS_ST];

    const int tid  = threadIdx.x;
    const int r    = tid >> 1;   // tile row this thread stages
    const int half = tid & 1;    // which 16-float k-half

    int ar = mt * 128 + r;
    if (ar >= ce) ar = ce - 1;
    const float* aptr = h + (size_t)tok_row[base + ar] * D_DIM + half * 16;
    const float* bgp  = ws + ((size_t)e * (2 * I_DIM) + (size_t)(nt * 128 + r)) * D_DIM + half * 16;
    const float* bup  = bgp + (size_t)I_DIM * D_DIM;

    unsigned short* aw  = &As[r * LDS_ST + half * 16];
    unsigned short* bgw = &Bg[r * LDS_ST + half * 16];
    unsigned short* buw = &Bu[r * LDS_ST + half * 16];

    const int wave = tid >> 6;
    const int lane = tid & 63;
    const int quad = lane >> 4;
    const int l16  = lane & 15;
    const int wm = (wave >> 1) * 64;
    const int wn = (wave & 1) * 64;

    floatx4 accg[4][4], accu[4][4];
#pragma unroll
    for (int i = 0; i < 4; ++i)
#pragma unroll
        for (int j = 0; j < 4; ++j) { accg[i][j] = (floatx4)0.f; accu[i][j] = (floatx4)0.f; }

    for (int k0 = 0; k0 < D_DIM; k0 += 32) {
        const float4* ap4 = reinterpret_cast<const float4*>(aptr + k0);
        const float4* bg4 = reinterpret_cast<const float4*>(bgp + k0);
        const float4* bu4 = reinterpret_cast<const float4*>(bup + k0);
        float4 a0 = ap4[0], a1 = ap4[1], a2 = ap4[2], a3 = ap4[3];
        float4 g0 = bg4[0], g1 = bg4[1], g2 = bg4[2], g3 = bg4[3];
        float4 u0 = bu4[0], u1 = bu4[1], u2 = bu4[2], u3 = bu4[3];
        __syncthreads();
        *reinterpret_cast<ushort8*>(aw)      = cvt8(a0, a1);
        *reinterpret_cast<ushort8*>(aw + 8)  = cvt8(a2, a3);
        *reinterpret_cast<ushort8*>(bgw)     = cvt8(g0, g1);
        *reinterpret_cast<ushort8*>(bgw + 8) = cvt8(g2, g3);
        *reinterpret_cast<ushort8*>(buw)     = cvt8(u0, u1);
        *reinterpret_cast<ushort8*>(buw + 8) = cvt8(u2, u3);
        __syncthreads();
        short8 a[4], bg[4], bu[4];
#pragma unroll
        for (int i = 0; i < 4; ++i)
            a[i] = *reinterpret_cast<const short8*>(&As[(wm + i * 16 + l16) * LDS_ST + quad * 8]);
#pragma unroll
        for (int j = 0; j < 4; ++j) {
            bg[j] = *reinterpret_cast<const short8*>(&Bg[(wn + j * 16 + l16) * LDS_ST + quad * 8]);
            bu[j] = *reinterpret_cast<const short8*>(&Bu[(wn + j * 16 + l16) * LDS_ST + quad * 8]);
        }
#pragma unroll
        for (int i = 0; i < 4; ++i)
#pragma unroll
            for (int j = 0; j < 4; ++j) {
                accg[i][j] = __builtin_amdgcn_mfma_f32_16x16x32_bf16(a[i], bg[j], accg[i][j], 0, 0, 0);
                accu[i][j] = __builtin_amdgcn_mfma_f32_16x16x32_bf16(a[i], bu[j], accu[i][j], 0, 0, 0);
            }
    }

    // epilogue: act = silu(gate) * up, bf16 store
#pragma unroll
    for (int i = 0; i < 4; ++i) {
#pragma unroll
        for (int reg = 0; reg < 4; ++reg) {
            const int gr = mt * 128 + wm + i * 16 + quad * 4 + reg;
            if (gr < ce) {
                const size_t rowoff = (size_t)(base + gr) * I_DIM;
#pragma unroll
                for (int j = 0; j < 4; ++j) {
                    float g = accg[i][j][reg];
                    float u = accu[i][j][reg];
                    float sa = g * u / (1.f + __expf(-g));
                    act[rowoff + nt * 128 + wn + j * 16 + l16] = f2bf(sa);
                }
            }
        }
    }
}

// ---------------- GEMM2: out[tok] += w * (act @ w2s[e].T) ----------------
__global__ __launch_bounds__(256) void down_kernel(
    const unsigned short* __restrict__ act, const float* __restrict__ w2s,
    const int* __restrict__ tok_row, const float* __restrict__ wt_row,
    const int* __restrict__ cnt, const int* __restrict__ off,
    float* __restrict__ out)
{
    const int e  = blockIdx.y >> 6;
    const int mt = blockIdx.y & 63;
    const int ce = cnt[e];
    if (mt * 128 >= ce) return;
    const int nt = blockIdx.x;
    const int base = off[e];

    __shared__ unsigned short As[128 * LDS_ST];
    __shared__ unsigned short Bs[128 * LDS_ST];

    const int tid  = threadIdx.x;
    const int r    = tid >> 1;
    const int half = tid & 1;

    int ar = mt * 128 + r;
    if (ar >= ce) ar = ce - 1;
    const unsigned short* aptr = act + (size_t)(base + ar) * I_DIM + half * 16;
    const float* bp = w2s + ((size_t)e * D_DIM + (size_t)(nt * 128 + r)) * I_DIM + half * 16;

    unsigned short* aw = &As[r * LDS_ST + half * 16];
    unsigned short* bw = &Bs[r * LDS_ST + half * 16];

    const int wave = tid >> 6;
    const int lane = tid & 63;
    const int quad = lane >> 4;
    const int l16  = lane & 15;
    const int wm = (wave >> 1) * 64;
    const int wn = (wave & 1) * 64;

    floatx4 acc[4][4];
#pragma unroll
    for (int i = 0; i < 4; ++i)
#pragma unroll
        for (int j = 0; j < 4; ++j) acc[i][j] = (floatx4)0.f;

    for (int k0 = 0; k0 < I_DIM; k0 += 32) {
        ushort8 av0 = *reinterpret_cast<const ushort8*>(aptr + k0);
        ushort8 av1 = *reinterpret_cast<const ushort8*>(aptr + k0 + 8);
        const float4* b4 = reinterpret_cast<const float4*>(bp + k0);
        float4 b0 = b4[0], b1 = b4[1], b2 = b4[2], b3 = b4[3];
        __syncthreads();
        *reinterpret_cast<ushort8*>(aw)     = av0;
        *reinterpret_cast<ushort8*>(aw + 8) = av1;
        *reinterpret_cast<ushort8*>(bw)     = cvt8(b0, b1);
        *reinterpret_cast<ushort8*>(bw + 8) = cvt8(b2, b3);
        __syncthreads();
        short8 a[4], b[4];
#pragma unroll
        for (int i = 0; i < 4; ++i)
            a[i] = *reinterpret_cast<const short8*>(&As[(wm + i * 16 + l16) * LDS_ST + quad * 8]);
#pragma unroll
        for (int j = 0; j < 4; ++j)
            b[j] = *reinterpret_cast<const short8*>(&Bs[(wn + j * 16 + l16) * LDS_ST + quad * 8]);
#pragma unroll
        for (int i = 0; i < 4; ++i)
#pragma unroll
            for (int j = 0; j < 4; ++j)
                acc[i][j] = __builtin_amdgcn_mfma_f32_16x16x32_bf16(a[i], b[j], acc[i][j], 0, 0, 0);
    }

#pragma unroll
    for (int i = 0; i < 4; ++i) {
#pragma unroll
        for (int reg = 0; reg < 4; ++reg) {
            const int gr = mt * 128 + wm + i * 16 + quad * 4 + reg;
            if (gr < ce) {
                const int tok = tok_row[base + gr];
                const float w = wt_row[base + gr];
                float* op = out + (size_t)tok * D_DIM + nt * 128 + wn;
#pragma unroll
                for (int j = 0; j < 4; ++j)
                    atomicAdd(&op[j * 16 + l16], acc[i][j][reg] * w);
            }
        }
    }
}

extern "C" void kernel_launch(void* const* d_in, const int* in_sizes, int n_in,
                              void* d_out, int out_size, void* d_ws, size_t ws_size,
                              hipStream_t stream)
{
    const float* h   = (const float*)d_in[0];
    const float* rw  = (const float*)d_in[1];
    const float* ws  = (const float*)d_in[2];
    const float* w2s = (const float*)d_in[3];
    float* out = (float*)d_out;

    char* wsb = (char*)d_ws;
    int*   cnt     = (int*)(wsb + 0);
    int*   cnt2    = (int*)(wsb + 32);
    int*   off     = (int*)(wsb + 64);
    int*   topk_id = (int*)(wsb + 256);
    float* topk_w  = (float*)(wsb + 256 + 65536);
    int*   tok_row = (int*)(wsb + 256 + 2 * 65536);
    float* wt_row  = (float*)(wsb + 256 + 3 * 65536);
    unsigned short* act = (unsigned short*)(wsb + 256 + 4 * 65536);  // [2T, I] bf16 = 128 MB

    hipMemsetAsync(wsb, 0, 256, stream);                                   // cnt/cnt2/off
    hipMemsetAsync(out, 0, (size_t)T_TOK * D_DIM * sizeof(float), stream); // accumulation target

    router_kernel<<<T_TOK / 4, 256, 0, stream>>>(h, rw, topk_id, topk_w);
    count_kernel<<<(2 * T_TOK) / 256, 256, 0, stream>>>(topk_id, cnt);
    prefix_kernel<<<1, 1, 0, stream>>>(cnt, off);
    scatter_kernel<<<(2 * T_TOK) / 256, 256, 0, stream>>>(topk_id, topk_w, off, cnt2, tok_row, wt_row);
    gateup_kernel<<<dim3(I_DIM / 128, E_EXP * 64), 256, 0, stream>>>(h, ws, tok_row, cnt, off, act);
    down_kernel<<<dim3(D_DIM / 128, E_EXP * 64), 256, 0, stream>>>(act, w2s, tok_row, wt_row, cnt, off, out);
}